// Round 7
// baseline (424.757 us; speedup 1.0000x reference)
//
#include <hip/hip_runtime.h>
#include <stdint.h>

// PointerNetwork forward, MI355X/gfx950.
// x-chain and h-chain are sampling-independent; scores for unvisited slots
// don't depend on WHICH slots are visited => precompute all, sample cheaply.
// B=256, S=64, H=128.
// RNG: JAX threefry2x32 partitionable mode: bits = o0^o1 of tf(key,(0,j)).
//
// Recurrent-kernel design note (R6 post-mortem): LDS cycles per step =
// 2304/M where M = m-rows/thread; M=1 (R6) was LDS-pipe-bound (96us).
// R7: within-lane-group K-split => M=6 (k3) / M=2+ (k1) with small VGPR
// weight slices (96/64 regs, no R5-style spills), conflict-free interleaved
// b128 broadcast reads, shfl_xor butterfly reduce, lane-local GRU tail.

#define BN 256
#define SN 64
#define HN 128
#define NEGV (-1.0e9f)
#define TINYF 1.17549435e-38f

__device__ __forceinline__ uint32_t rotl32(uint32_t v, int d) {
  return (v << d) | (v >> (32 - d));
}

__device__ __forceinline__ void threefry2x32(uint32_t k0, uint32_t k1,
                                             uint32_t x0, uint32_t x1,
                                             uint32_t& o0, uint32_t& o1) {
  uint32_t ks2 = k0 ^ k1 ^ 0x1BD11BDAu;
  x0 += k0; x1 += k1;
  x0 += x1; x1 = rotl32(x1, 13); x1 ^= x0;
  x0 += x1; x1 = rotl32(x1, 15); x1 ^= x0;
  x0 += x1; x1 = rotl32(x1, 26); x1 ^= x0;
  x0 += x1; x1 = rotl32(x1, 6);  x1 ^= x0;
  x0 += k1; x1 += ks2 + 1u;
  x0 += x1; x1 = rotl32(x1, 17); x1 ^= x0;
  x0 += x1; x1 = rotl32(x1, 29); x1 ^= x0;
  x0 += x1; x1 = rotl32(x1, 16); x1 ^= x0;
  x0 += x1; x1 = rotl32(x1, 24); x1 ^= x0;
  x0 += ks2; x1 += k0 + 2u;
  x0 += x1; x1 = rotl32(x1, 13); x1 ^= x0;
  x0 += x1; x1 = rotl32(x1, 15); x1 ^= x0;
  x0 += x1; x1 = rotl32(x1, 26); x1 ^= x0;
  x0 += x1; x1 = rotl32(x1, 6);  x1 ^= x0;
  x0 += k0; x1 += k1 + 3u;
  x0 += x1; x1 = rotl32(x1, 17); x1 ^= x0;
  x0 += x1; x1 = rotl32(x1, 29); x1 ^= x0;
  x0 += x1; x1 = rotl32(x1, 16); x1 ^= x0;
  x0 += x1; x1 = rotl32(x1, 24); x1 ^= x0;
  x0 += k1; x1 += ks2 + 4u;
  x0 += x1; x1 = rotl32(x1, 13); x1 ^= x0;
  x0 += x1; x1 = rotl32(x1, 15); x1 ^= x0;
  x0 += x1; x1 = rotl32(x1, 26); x1 ^= x0;
  x0 += x1; x1 = rotl32(x1, 6);  x1 ^= x0;
  x0 += ks2; x1 += k0 + 5u;
  o0 = x0; o1 = x1;
}

__device__ __forceinline__ float jax_gumbel(uint32_t k0, uint32_t k1, int j) {
  uint32_t o0, o1;
  threefry2x32(k0, k1, 0u, (uint32_t)j, o0, o1);
  uint32_t bits = o0 ^ o1;
  uint32_t ub = (bits >> 9) | 0x3F800000u;
  float u = __uint_as_float(ub) - 1.0f;
  u = fmaxf(u + TINYF, TINYF);
  return -logf(-logf(u));
}

// fast tanh: (1-e)/(1+e), e=exp(-2|x|) in (0,1]; ~2ulp
__device__ __forceinline__ float ftanh(float x) {
  float ax = fabsf(x);
  float e = __expf(-2.0f * ax);
  float r = (1.0f - e) * __builtin_amdgcn_rcpf(1.0f + e);
  return copysignf(r, x);
}

__device__ __forceinline__ float fsig(float x) {
  return __builtin_amdgcn_rcpf(1.0f + __expf(-x));
}

// ---------------- K0: fold dyn path + step keys ----------------
__global__ void k0_dyn(const float* __restrict__ W_att, const float* __restrict__ dyn_w,
                       const float* __restrict__ dyn_b, float* __restrict__ Wd,
                       float* __restrict__ cv, uint32_t* __restrict__ keys) {
  int h = threadIdx.x;  // 128
  if (h < 64) {
    uint32_t o0, o1;
    threefry2x32(0u, 42u, 0u, (uint32_t)h, o0, o1);
    keys[2 * h] = o0; keys[2 * h + 1] = o1;
  }
  float w0 = 0.f, w1 = 0.f, cc = 0.f;
  for (int k = 0; k < HN; ++k) {
    float w = W_att[h * 384 + 128 + k];
    w0 = fmaf(w, dyn_w[2 * k + 0], w0);
    w1 = fmaf(w, dyn_w[2 * k + 1], w1);
    cc = fmaf(w, dyn_b[k], cc);
  }
  Wd[2 * h] = w0; Wd[2 * h + 1] = w1; cv[h] = cc;
}

// ---------------- K1: x-chain v2: 256 thr = 64 ml x 4 ks ----------------
// thread (ml, ks): m-rows {ml, ml+64}, k-slice {q*16 + ks*4 + j}, q 0..7.
// 64 weight VGPRs. 8 conflict-free b128 broadcasts/step. shfl_xor(1,2) reduce.
__global__ __launch_bounds__(256) void k1_xchain(const float* __restrict__ SE,
                                                 const float* __restrict__ in_w,
                                                 const float* __restrict__ in_b,
                                                 float* __restrict__ X) {
  __shared__ float xc[HN];
  int b = blockIdx.x, t = threadIdx.x;
  int ks = t & 3, ml = t >> 2;
  float4 wv0[8], wv1[8];
#pragma unroll
  for (int q = 0; q < 8; ++q) {
    wv0[q] = *(const float4*)(in_w + (ml)      * HN + q * 16 + ks * 4);
    wv1[q] = *(const float4*)(in_w + (ml + 64) * HN + q * 16 + ks * 4);
  }
  float bt0 = in_b[ml], bt1 = in_b[ml + 64];
  if (t < HN) xc[t] = SE[(b * HN + t) * SN + 0];
  __syncthreads();
  for (int i = 0; i < SN; ++i) {
    float a00 = 0.f, a01 = 0.f, a02 = 0.f, a03 = 0.f;
    float a10 = 0.f, a11 = 0.f, a12 = 0.f, a13 = 0.f;
#pragma unroll
    for (int q = 0; q < 8; ++q) {
      float4 x4 = *(const float4*)(xc + q * 16 + ks * 4);
      a00 = fmaf(wv0[q].x, x4.x, a00);
      a01 = fmaf(wv0[q].y, x4.y, a01);
      a02 = fmaf(wv0[q].z, x4.z, a02);
      a03 = fmaf(wv0[q].w, x4.w, a03);
      a10 = fmaf(wv1[q].x, x4.x, a10);
      a11 = fmaf(wv1[q].y, x4.y, a11);
      a12 = fmaf(wv1[q].z, x4.z, a12);
      a13 = fmaf(wv1[q].w, x4.w, a13);
    }
    float s0 = (a00 + a01) + (a02 + a03);
    float s1 = (a10 + a11) + (a12 + a13);
    s0 += __shfl_xor(s0, 1); s0 += __shfl_xor(s0, 2);
    s1 += __shfl_xor(s1, 1); s1 += __shfl_xor(s1, 2);
    __syncthreads();
    if (ks == 0) {
      float x0 = s0 + bt0, x1 = s1 + bt1;
      float* Xr = X + (i * BN + b) * HN;
      Xr[ml] = x0; Xr[ml + 64] = x1;
      xc[ml] = x0; xc[ml + 64] = x1;
    }
    __syncthreads();
  }
}

// ---------------- universal GEMM: C[n][m] = sum_k A[n][k]*W[m][wofs+k] ------
__global__ __launch_bounds__(256, 3) void gemm_u(const float* __restrict__ A,
                                                 const float* __restrict__ W,
                                                 const float* __restrict__ bias,
                                                 float* __restrict__ C,
                                                 int ldw, int wofs, int Mtot) {
  __shared__ float4 xsv[64 * 32];  // 64 n-rows x 128 k (32 KB)
  int n0 = blockIdx.x * 64, mo = blockIdx.y * 128;
  int t = threadIdx.x, ml = t >> 2, ks = t & 3;
  int m0 = mo + ml, m1 = mo + 64 + ml;
  float4 wv0[8], wv1[8];
#pragma unroll
  for (int kk = 0; kk < 8; ++kk) {
    wv0[kk] = *(const float4*)(W + m0 * ldw + wofs + kk * 16 + ks * 4);
    wv1[kk] = *(const float4*)(W + m1 * ldw + wofs + kk * 16 + ks * 4);
  }
  float b0 = bias ? bias[m0] : 0.f;
  float b1 = bias ? bias[m1] : 0.f;
  const float4* Av = (const float4*)(A + n0 * HN);
#pragma unroll
  for (int p = 0; p < 8; ++p) xsv[p * 256 + t] = Av[p * 256 + t];
  __syncthreads();
  for (int n = 0; n < 64; ++n) {
    const float4* xr = xsv + n * 32 + ks;
    float a00 = 0.f, a01 = 0.f, a10 = 0.f, a11 = 0.f;
#pragma unroll
    for (int kk = 0; kk < 8; ++kk) {
      float4 x4 = xr[kk * 4];
      a00 = fmaf(wv0[kk].x, x4.x, a00);
      a01 = fmaf(wv0[kk].y, x4.y, a01);
      a00 = fmaf(wv0[kk].z, x4.z, a00);
      a01 = fmaf(wv0[kk].w, x4.w, a01);
      a10 = fmaf(wv1[kk].x, x4.x, a10);
      a11 = fmaf(wv1[kk].y, x4.y, a11);
      a10 = fmaf(wv1[kk].z, x4.z, a10);
      a11 = fmaf(wv1[kk].w, x4.w, a11);
    }
    float v0 = a00 + a01, v1 = a10 + a11;
    v0 += __shfl_xor(v0, 1); v0 += __shfl_xor(v0, 2);
    v1 += __shfl_xor(v1, 1); v1 += __shfl_xor(v1, 2);
    if (ks == 0) {
      C[(n0 + n) * Mtot + m0] = v0 + b0;
      C[(n0 + n) * Mtot + m1] = v1 + b1;
    }
  }
}

// ---------------- kT: SET[(b*64+s)*128+h] = SE[b][h][s] (LDS transpose) -----
__global__ __launch_bounds__(256) void kT(const float* __restrict__ SE,
                                          float* __restrict__ SET) {
  __shared__ float ls[HN * 66];
  int b = blockIdx.x, t = threadIdx.x;
#pragma unroll
  for (int p = 0; p < 32; ++p) {
    int idx = p * 256 + t;
    int h = idx >> 6, s = idx & 63;
    ls[h * 66 + s] = SE[b * 8192 + idx];
  }
  __syncthreads();
#pragma unroll
  for (int p = 0; p < 32; ++p) {
    int idx = p * 256 + t;
    int s = idx >> 7, h = idx & 127;
    SET[b * 8192 + idx] = ls[h * 66 + s];
  }
}

// ---------------- K3: h-chain v2: 512 thr = 64 ml x 8 ks ----------------
// thread (ml, ks): m-rows {ml+64j, j=0..5}, k-slice {q*32 + ks*4 + j}, q 0..3.
// 96 weight VGPRs. 4 conflict-free b128 broadcasts/step. shfl_xor(1,2,4).
// Tail lane-local: m=ml+64j covers (r,z,n) for h=ml (j even) and ml+64 (j odd).
__global__ __launch_bounds__(512, 2) void k3_hchain(const float* __restrict__ GI,
                                                    const float* __restrict__ w_hh,
                                                    const float* __restrict__ b_hh,
                                                    float* __restrict__ Hs) {
  __shared__ float hc[HN];
  int b = blockIdx.x, t = threadIdx.x;
  int ks = t & 7, ml = t >> 3;
  float4 wv[6][4];
#pragma unroll
  for (int j = 0; j < 6; ++j)
#pragma unroll
    for (int q = 0; q < 4; ++q)
      wv[j][q] = *(const float4*)(w_hh + (ml + 64 * j) * HN + q * 32 + ks * 4);
  float bt[6];
#pragma unroll
  for (int j = 0; j < 6; ++j) bt[j] = b_hh[ml + 64 * j];
  if (t < HN) hc[t] = 0.f;
  // GI prefetch (only ks==0 consumes; depth-2)
  float g0[6], g1[6];
  if (ks == 0) {
#pragma unroll
    for (int j = 0; j < 6; ++j) {
      g0[j] = GI[(0 * BN + b) * 384 + ml + 64 * j];
      g1[j] = GI[(1 * BN + b) * 384 + ml + 64 * j];
    }
  }
  float hp0 = 0.f, hp1 = 0.f;  // previous h[ml], h[ml+64] (ks==0 lanes)
  __syncthreads();
  for (int i = 0; i < SN; ++i) {
    float4 x4[4];
#pragma unroll
    for (int q = 0; q < 4; ++q) x4[q] = *(const float4*)(hc + q * 32 + ks * 4);
    float sum[6];
#pragma unroll
    for (int j = 0; j < 6; ++j) {
      float a0 = 0.f, a1 = 0.f, a2 = 0.f, a3 = 0.f;
#pragma unroll
      for (int q = 0; q < 4; ++q) {
        a0 = fmaf(wv[j][q].x, x4[q].x, a0);
        a1 = fmaf(wv[j][q].y, x4[q].y, a1);
        a2 = fmaf(wv[j][q].z, x4[q].z, a2);
        a3 = fmaf(wv[j][q].w, x4[q].w, a3);
      }
      float s = (a0 + a1) + (a2 + a3);
      s += __shfl_xor(s, 1); s += __shfl_xor(s, 2); s += __shfl_xor(s, 4);
      sum[j] = s + bt[j];
    }
    __syncthreads();  // all hc reads done before rewrite
    if (ks == 0) {
      // h = ml  : r=sum[0]+gi, z=sum[2]+gi, n=gi + r*sum[4]
      float r0 = fsig(g0[0] + sum[0]);
      float z0 = fsig(g0[2] + sum[2]);
      float n0 = ftanh(g0[4] + r0 * sum[4]);
      float hn0 = (1.0f - z0) * n0 + z0 * hp0;
      // h = ml+64
      float r1 = fsig(g0[1] + sum[1]);
      float z1 = fsig(g0[3] + sum[3]);
      float n1 = ftanh(g0[5] + r1 * sum[5]);
      float hn1 = (1.0f - z1) * n1 + z1 * hp1;
      hc[ml] = hn0; hc[ml + 64] = hn1;
      float* Hr = Hs + (i * BN + b) * HN;
      Hr[ml] = hn0; Hr[ml + 64] = hn1;
      hp0 = hn0; hp1 = hn1;
#pragma unroll
      for (int j = 0; j < 6; ++j) {
        g0[j] = g1[j];
        g1[j] = (i + 2 < SN) ? GI[((i + 2) * BN + b) * 384 + ml + 64 * j] : 0.f;
      }
    }
    __syncthreads();
  }
}

// ---------------- K6: scores P[b][i][s], 8 i per block ----------------
__global__ __launch_bounds__(256) void k6_scores(const float* __restrict__ Ust,
                                                 const float* __restrict__ WhC,
                                                 const float* __restrict__ dynamic,
                                                 const float* __restrict__ Wd,
                                                 const float* __restrict__ cv,
                                                 const float* __restrict__ v_att,
                                                 float* __restrict__ Pg) {
  __shared__ float U[HN * 65];
  __shared__ float Wh[8 * HN];
  __shared__ float sv[HN];
  int b = blockIdx.x, iq = blockIdx.y, t = threadIdx.x;
#pragma unroll
  for (int p = 0; p < 32; ++p) {
    int idx = p * 256 + t;
    int s = idx >> 7, h = idx & 127;
    float u = Ust[(b * SN + s) * HN + h];
    float d0 = dynamic[(b * 2 + 0) * SN + s];
    float d1 = dynamic[(b * 2 + 1) * SN + s];
    u += Wd[2 * h] * d0 + Wd[2 * h + 1] * d1 + cv[h];
    U[h * 65 + s] = u;
  }
#pragma unroll
  for (int p = 0; p < 4; ++p) {
    int idx = p * 256 + t;
    int i = idx >> 7, h = idx & 127;
    Wh[i * HN + h] = WhC[((iq * 8 + i) * BN + b) * HN + h];
  }
  if (t < HN) sv[t] = v_att[t];
  __syncthreads();
  int s = t & 63, w = t >> 6;
  float acc0 = 0.f, acc1 = 0.f;
  for (int h = 0; h < HN; h += 4) {
    float u0 = U[(h + 0) * 65 + s];
    float u1 = U[(h + 1) * 65 + s];
    float u2 = U[(h + 2) * 65 + s];
    float u3 = U[(h + 3) * 65 + s];
    float4 v4 = *(const float4*)&sv[h];
    float4 wa = *(const float4*)&Wh[(w * 2 + 0) * HN + h];
    acc0 = fmaf(v4.x, ftanh(u0 + wa.x), acc0);
    acc0 = fmaf(v4.y, ftanh(u1 + wa.y), acc0);
    acc0 = fmaf(v4.z, ftanh(u2 + wa.z), acc0);
    acc0 = fmaf(v4.w, ftanh(u3 + wa.w), acc0);
    float4 wb = *(const float4*)&Wh[(w * 2 + 1) * HN + h];
    acc1 = fmaf(v4.x, ftanh(u0 + wb.x), acc1);
    acc1 = fmaf(v4.y, ftanh(u1 + wb.y), acc1);
    acc1 = fmaf(v4.z, ftanh(u2 + wb.z), acc1);
    acc1 = fmaf(v4.w, ftanh(u3 + wb.w), acc1);
  }
  int i0 = iq * 8 + w * 2;
  Pg[b * 4096 + (i0 + 0) * 64 + s] = acc0;
  Pg[b * 4096 + (i0 + 1) * 64 + s] = acc1;
}

// ---------------- K7: gumbel + sampling (one wave per batch element) --------
__global__ __launch_bounds__(256) void k7_sample(const float* __restrict__ Pg,
                                                 const uint32_t* __restrict__ keys,
                                                 float* __restrict__ out) {
  __shared__ float Pl[4096];
  __shared__ float Gl[4096];
  int b = blockIdx.x, t = threadIdx.x;
#pragma unroll
  for (int p = 0; p < 4; ++p)
    ((float4*)Pl)[p * 256 + t] = ((const float4*)(Pg + b * 4096))[p * 256 + t];
  for (int p = 0; p < 16; ++p) {
    int idx = p * 256 + t;
    int i = idx >> 6;
    Gl[idx] = jax_gumbel(keys[2 * i], keys[2 * i + 1], b * 64 + (idx & 63));
  }
  __syncthreads();
  if (t < 64) {
    int s = t;
    bool visited = false;
    for (int i = 0; i < SN; ++i) {
      float score = Pl[i * 64 + s];
      bool allowed = (i == 0) ? (s == 0) : (!visited);
      float logit = allowed ? score : NEGV;
      float z = logit + Gl[i * 64 + s];
      float bz = z; int bi = s;
#pragma unroll
      for (int off = 32; off > 0; off >>= 1) {
        float oz = __shfl_xor(bz, off);
        int oi = __shfl_xor(bi, off);
        if (oz > bz || (oz == bz && oi < bi)) { bz = oz; bi = oi; }
      }
      int ptr = bi;
      float m = logit;
#pragma unroll
      for (int off = 32; off > 0; off >>= 1) m = fmaxf(m, __shfl_xor(m, off));
      float e = expf(logit - m);
      float sum = e;
#pragma unroll
      for (int off = 32; off > 0; off >>= 1) sum += __shfl_xor(sum, off);
      float chosen = __shfl(logit, ptr);
      float logp = (chosen - m) - logf(sum);
      if (s == ptr) visited = true;
      if (s == 0) {
        out[b * SN + i] = (float)ptr;
        out[BN * SN + b * SN + i] = logp;
      }
    }
  }
}

// ---------------- launch ----------------
extern "C" void kernel_launch(void* const* d_in, const int* in_sizes, int n_in,
                              void* d_out, int out_size, void* d_ws, size_t ws_size,
                              hipStream_t stream) {
  const float* SE    = (const float*)d_in[1];
  const float* dynam = (const float*)d_in[2];
  const float* dyn_w = (const float*)d_in[3];
  const float* dyn_b = (const float*)d_in[4];
  const float* in_w  = (const float*)d_in[5];
  const float* in_b  = (const float*)d_in[6];
  const float* w_ih  = (const float*)d_in[7];
  const float* w_hh  = (const float*)d_in[8];
  const float* b_ih  = (const float*)d_in[9];
  const float* b_hh  = (const float*)d_in[10];
  const float* W_att = (const float*)d_in[11];
  const float* v_att = (const float*)d_in[12];
  float* out = (float*)d_out;
  float* ws = (float*)d_ws;

  // workspace (floats), lifetime-aliased:
  //  [0, 2M)           X (k1->gemm GI), Hs (k3->gemm WhC), P (k6->k7)
  //  [2M, 8.29M)       GI (gemm->k3); after k3: SET@2M, WhC@4M, Ust@6M
  //  [8.39M, +)        Wd, cv, keys
  float* X   = ws;
  float* GI  = ws + 2097152;
  float* SET = ws + 2097152;
  float* WhC = ws + 4194304;
  float* Ust = ws + 6291456;
  float* Wd  = ws + 8388608;
  float* cv  = Wd + 256;
  uint32_t* keys = (uint32_t*)(cv + 128);
  float* Hs  = X;
  float* P   = X;

  hipLaunchKernelGGL(k0_dyn, dim3(1), dim3(128), 0, stream, W_att, dyn_w, dyn_b, Wd, cv, keys);
  hipLaunchKernelGGL(k1_xchain, dim3(BN), dim3(256), 0, stream, SE, in_w, in_b, X);
  hipLaunchKernelGGL(gemm_u, dim3(256, 3), dim3(256), 0, stream,
                     X, w_ih, b_ih, GI, HN, 0, 384);
  hipLaunchKernelGGL(k3_hchain, dim3(BN), dim3(512), 0, stream, GI, w_hh, b_hh, Hs);
  hipLaunchKernelGGL(kT, dim3(BN), dim3(256), 0, stream, SE, SET);
  hipLaunchKernelGGL(gemm_u, dim3(256, 1), dim3(256), 0, stream,
                     Hs, W_att, (const float*)nullptr, WhC, 384, 256, HN);
  hipLaunchKernelGGL(gemm_u, dim3(256, 1), dim3(256), 0, stream,
                     SET, W_att, (const float*)nullptr, Ust, 384, 0, HN);
  hipLaunchKernelGGL(k6_scores, dim3(BN, 8), dim3(256), 0, stream,
                     Ust, WhC, dynam, Wd, cv, v_att, P);
  hipLaunchKernelGGL(k7_sample, dim3(BN), dim3(256), 0, stream, P, keys, out);
}

// Round 8
// 359.152 us; speedup vs baseline: 1.1827x; 1.1827x over previous
//
#include <hip/hip_runtime.h>
#include <stdint.h>

// PointerNetwork forward, MI355X/gfx950 — SINGLE FUSED KERNEL.
// Insight (R7 post-mortem): every phase is batch-parallel; all intermediates
// per batch fit in LDS (137 KB). One block per batch => zero global traffic
// between phases, no per-step global-load/store barrier drains, 2 dispatches
// instead of 9. Chains use 1 barrier/step (double-buffered state).
// B=256, S=64, H=128.
// RNG: JAX threefry2x32 partitionable mode: bits = o0^o1 of tf(key,(0,j)).

#define BN 256
#define SN 64
#define HN 128
#define NEGV (-1.0e9f)
#define TINYF 1.17549435e-38f

// LDS layout (floats). Lifetime aliasing:
//  A [0,8192): X (P0-P1) / H (P2-P3) / P+G (P6-P8)
//  B [8192,33280): GI (P1-P2) / WhC@8192, seT@16384, U_t@24832 (P3+)
#define OFF_A   0
#define OFF_GI  8192
#define OFF_WHC 8192
#define OFF_SET 16384
#define OFF_UT  24832
#define OFF_HC  33280   // 2*128 double-buffered x/h state
#define OFF_KK  33536   // 128 (uint32 keys)
#define OFF_SV  33664   // 128 v_att
#define OFF_DY  33792   // 128 dynamic[b]
#define OFF_WD  33920   // 256 Wd
#define OFF_CV  34176   // 128 cv
#define SMEM_FLOATS 34304   // 137216 B

__device__ __forceinline__ uint32_t rotl32(uint32_t v, int d) {
  return (v << d) | (v >> (32 - d));
}

__device__ __forceinline__ void threefry2x32(uint32_t k0, uint32_t k1,
                                             uint32_t x0, uint32_t x1,
                                             uint32_t& o0, uint32_t& o1) {
  uint32_t ks2 = k0 ^ k1 ^ 0x1BD11BDAu;
  x0 += k0; x1 += k1;
  x0 += x1; x1 = rotl32(x1, 13); x1 ^= x0;
  x0 += x1; x1 = rotl32(x1, 15); x1 ^= x0;
  x0 += x1; x1 = rotl32(x1, 26); x1 ^= x0;
  x0 += x1; x1 = rotl32(x1, 6);  x1 ^= x0;
  x0 += k1; x1 += ks2 + 1u;
  x0 += x1; x1 = rotl32(x1, 17); x1 ^= x0;
  x0 += x1; x1 = rotl32(x1, 29); x1 ^= x0;
  x0 += x1; x1 = rotl32(x1, 16); x1 ^= x0;
  x0 += x1; x1 = rotl32(x1, 24); x1 ^= x0;
  x0 += ks2; x1 += k0 + 2u;
  x0 += x1; x1 = rotl32(x1, 13); x1 ^= x0;
  x0 += x1; x1 = rotl32(x1, 15); x1 ^= x0;
  x0 += x1; x1 = rotl32(x1, 26); x1 ^= x0;
  x0 += x1; x1 = rotl32(x1, 6);  x1 ^= x0;
  x0 += k0; x1 += k1 + 3u;
  x0 += x1; x1 = rotl32(x1, 17); x1 ^= x0;
  x0 += x1; x1 = rotl32(x1, 29); x1 ^= x0;
  x0 += x1; x1 = rotl32(x1, 16); x1 ^= x0;
  x0 += x1; x1 = rotl32(x1, 24); x1 ^= x0;
  x0 += k1; x1 += ks2 + 4u;
  x0 += x1; x1 = rotl32(x1, 13); x1 ^= x0;
  x0 += x1; x1 = rotl32(x1, 15); x1 ^= x0;
  x0 += x1; x1 = rotl32(x1, 26); x1 ^= x0;
  x0 += x1; x1 = rotl32(x1, 6);  x1 ^= x0;
  x0 += ks2; x1 += k0 + 5u;
  o0 = x0; o1 = x1;
}

__device__ __forceinline__ float jax_gumbel(uint32_t k0, uint32_t k1, int j) {
  uint32_t o0, o1;
  threefry2x32(k0, k1, 0u, (uint32_t)j, o0, o1);
  uint32_t bits = o0 ^ o1;
  uint32_t ub = (bits >> 9) | 0x3F800000u;
  float u = __uint_as_float(ub) - 1.0f;
  u = fmaxf(u + TINYF, TINYF);
  return -logf(-logf(u));
}

__device__ __forceinline__ float ftanh(float x) {
  float ax = fabsf(x);
  float e = __expf(-2.0f * ax);
  float r = (1.0f - e) * __builtin_amdgcn_rcpf(1.0f + e);
  return copysignf(r, x);
}

__device__ __forceinline__ float fsig(float x) {
  return __builtin_amdgcn_rcpf(1.0f + __expf(-x));
}

// ---------------- K0: fold dyn path through W_att2 (tiny) ----------------
__global__ void k0_dyn(const float* __restrict__ W_att, const float* __restrict__ dyn_w,
                       const float* __restrict__ dyn_b, float* __restrict__ Wd,
                       float* __restrict__ cv) {
  int h = threadIdx.x;  // 128
  float w0 = 0.f, w1 = 0.f, cc = 0.f;
  for (int k = 0; k < HN; ++k) {
    float w = W_att[h * 384 + 128 + k];
    w0 = fmaf(w, dyn_w[2 * k + 0], w0);
    w1 = fmaf(w, dyn_w[2 * k + 1], w1);
    cc = fmaf(w, dyn_b[k], cc);
  }
  Wd[2 * h] = w0; Wd[2 * h + 1] = w1; cv[h] = cc;
}

// ---------------- MEGA: everything for batch b in one block ----------------
__global__ __launch_bounds__(512, 1) void mega(
    const float* __restrict__ SE, const float* __restrict__ dynamic,
    const float* __restrict__ in_w, const float* __restrict__ in_b,
    const float* __restrict__ w_ih, const float* __restrict__ b_ih,
    const float* __restrict__ w_hh, const float* __restrict__ b_hh,
    const float* __restrict__ W_att, const float* __restrict__ v_att,
    const float* __restrict__ Wd, const float* __restrict__ cv,
    float* __restrict__ out) {
  extern __shared__ float sm[];
  int b = blockIdx.x, t = threadIdx.x;
  float* A   = sm + OFF_A;
  float* GIl = sm + OFF_GI;
  float* WHC = sm + OFF_WHC;
  float* SET = sm + OFF_SET;
  float* UT  = sm + OFF_UT;
  float* HC  = sm + OFF_HC;
  uint32_t* KK = (uint32_t*)(sm + OFF_KK);
  float* SV  = sm + OFF_SV;
  float* DY  = sm + OFF_DY;
  float* WDs = sm + OFF_WD;
  float* CVs = sm + OFF_CV;

  // ---- staging ----
  if (t < 64) {
    uint32_t o0, o1;
    threefry2x32(0u, 42u, 0u, (uint32_t)t, o0, o1);   // fold_in(key(42), i=t)
    KK[2 * t] = o0; KK[2 * t + 1] = o1;
  }
  if (t < 128) {
    SV[t]  = v_att[t];
    DY[t]  = dynamic[b * 128 + t];
    CVs[t] = cv[t];
    HC[t]  = SE[b * 8192 + t * 64];   // x_{-1} = SE[b,:,0] into buf0
  }
  if (t < 256) WDs[t] = Wd[t];
  __syncthreads();

  // ---- P0: x-chain. 512 thr = 128 ml x 4 ks; k-slice q*16+ks*4, q<8 ----
  {
    int ml = t >> 2, ks = t & 3;
    float4 wv[8];
#pragma unroll
    for (int q = 0; q < 8; ++q)
      wv[q] = *(const float4*)(in_w + ml * HN + q * 16 + ks * 4);
    float bib = in_b[ml];
    for (int ii = 0; ii < SN; ++ii) {
      const float* xc = HC + (ii & 1) * 128;
      float* xn = HC + ((ii + 1) & 1) * 128;
      float a0 = 0.f, a1 = 0.f, a2 = 0.f, a3 = 0.f;
#pragma unroll
      for (int q = 0; q < 8; ++q) {
        float4 x4 = *(const float4*)(xc + q * 16 + ks * 4);
        a0 = fmaf(wv[q].x, x4.x, a0);
        a1 = fmaf(wv[q].y, x4.y, a1);
        a2 = fmaf(wv[q].z, x4.z, a2);
        a3 = fmaf(wv[q].w, x4.w, a3);
      }
      float s = (a0 + a1) + (a2 + a3);
      s += __shfl_xor(s, 1); s += __shfl_xor(s, 2);
      if (ks == 0) {
        float xv = s + bib;
        A[ii * 128 + ml] = xv;   // X history
        xn[ml] = xv;
      }
      __syncthreads();
    }
  }

  // ---- P1: GI = w_ih @ X + b_ih (bulk). 64 ml x 8 ks; 6 m-rows ----
  {
    int ml = t >> 3, ks = t & 7;
    float4 wv[6][4]; float bi[6];
#pragma unroll
    for (int j = 0; j < 6; ++j) {
#pragma unroll
      for (int q = 0; q < 4; ++q)
        wv[j][q] = *(const float4*)(w_ih + (ml + 64 * j) * HN + q * 32 + ks * 4);
      bi[j] = b_ih[ml + 64 * j];
    }
    for (int n = 0; n < SN; ++n) {
      float4 x4[4];
#pragma unroll
      for (int q = 0; q < 4; ++q)
        x4[q] = *(const float4*)(A + n * 128 + q * 32 + ks * 4);
      float sum[6];
#pragma unroll
      for (int j = 0; j < 6; ++j) {
        float a0 = 0.f, a1 = 0.f, a2 = 0.f, a3 = 0.f;
#pragma unroll
        for (int q = 0; q < 4; ++q) {
          a0 = fmaf(wv[j][q].x, x4[q].x, a0);
          a1 = fmaf(wv[j][q].y, x4[q].y, a1);
          a2 = fmaf(wv[j][q].z, x4[q].z, a2);
          a3 = fmaf(wv[j][q].w, x4[q].w, a3);
        }
        float s = (a0 + a1) + (a2 + a3);
        s += __shfl_xor(s, 1); s += __shfl_xor(s, 2); s += __shfl_xor(s, 4);
        sum[j] = s + bi[j];
      }
      if (ks == 0) {
#pragma unroll
        for (int j = 0; j < 6; ++j) GIl[n * 384 + ml + 64 * j] = sum[j];
      }
    }
    __syncthreads();
  }

  // ---- P2: h-chain (GRU). GI in LDS; H history -> A (X dead) ----
  if (t < 256) HC[t] = 0.f;
  __syncthreads();
  {
    int ml = t >> 3, ks = t & 7;
    float4 wv[6][4]; float bh[6];
#pragma unroll
    for (int j = 0; j < 6; ++j) {
#pragma unroll
      for (int q = 0; q < 4; ++q)
        wv[j][q] = *(const float4*)(w_hh + (ml + 64 * j) * HN + q * 32 + ks * 4);
      bh[j] = b_hh[ml + 64 * j];
    }
    float hp0 = 0.f, hp1 = 0.f;
    for (int ii = 0; ii < SN; ++ii) {
      const float* hcr = HC + (ii & 1) * 128;
      float* hcw = HC + ((ii + 1) & 1) * 128;
      float4 x4[4];
#pragma unroll
      for (int q = 0; q < 4; ++q)
        x4[q] = *(const float4*)(hcr + q * 32 + ks * 4);
      float sum[6];
#pragma unroll
      for (int j = 0; j < 6; ++j) {
        float a0 = 0.f, a1 = 0.f, a2 = 0.f, a3 = 0.f;
#pragma unroll
        for (int q = 0; q < 4; ++q) {
          a0 = fmaf(wv[j][q].x, x4[q].x, a0);
          a1 = fmaf(wv[j][q].y, x4[q].y, a1);
          a2 = fmaf(wv[j][q].z, x4[q].z, a2);
          a3 = fmaf(wv[j][q].w, x4[q].w, a3);
        }
        float s = (a0 + a1) + (a2 + a3);
        s += __shfl_xor(s, 1); s += __shfl_xor(s, 2); s += __shfl_xor(s, 4);
        sum[j] = s + bh[j];
      }
      if (ks == 0) {
        const float* gr = GIl + ii * 384;
        float r0 = fsig(gr[ml] + sum[0]);
        float z0 = fsig(gr[128 + ml] + sum[2]);
        float n0 = ftanh(gr[256 + ml] + r0 * sum[4]);
        float hn0 = (1.0f - z0) * n0 + z0 * hp0;
        float r1 = fsig(gr[64 + ml] + sum[1]);
        float z1 = fsig(gr[192 + ml] + sum[3]);
        float n1 = ftanh(gr[320 + ml] + r1 * sum[5]);
        float hn1 = (1.0f - z1) * n1 + z1 * hp1;
        hcw[ml] = hn0; hcw[ml + 64] = hn1;
        A[ii * 128 + ml] = hn0; A[ii * 128 + ml + 64] = hn1;  // H history
        hp0 = hn0; hp1 = hn1;
      }
      __syncthreads();
    }
  }

  // ---- P3: WhC = W_att3 @ H (bulk). 64 ml x 8 ks; 2 m-rows ----
  {
    int ml = t >> 3, ks = t & 7;
    float4 w0[4], w1[4];
#pragma unroll
    for (int q = 0; q < 4; ++q) {
      w0[q] = *(const float4*)(W_att + (ml)      * 384 + 256 + q * 32 + ks * 4);
      w1[q] = *(const float4*)(W_att + (ml + 64) * 384 + 256 + q * 32 + ks * 4);
    }
    for (int n = 0; n < SN; ++n) {
      float4 x4[4];
#pragma unroll
      for (int q = 0; q < 4; ++q)
        x4[q] = *(const float4*)(A + n * 128 + q * 32 + ks * 4);
      float a00 = 0.f, a01 = 0.f, a10 = 0.f, a11 = 0.f;
#pragma unroll
      for (int q = 0; q < 4; ++q) {
        a00 = fmaf(w0[q].x, x4[q].x, a00);
        a01 = fmaf(w0[q].y, x4[q].y, a01);
        a00 = fmaf(w0[q].z, x4[q].z, a00);
        a01 = fmaf(w0[q].w, x4[q].w, a01);
        a10 = fmaf(w1[q].x, x4[q].x, a10);
        a11 = fmaf(w1[q].y, x4[q].y, a11);
        a10 = fmaf(w1[q].z, x4[q].z, a10);
        a11 = fmaf(w1[q].w, x4[q].w, a11);
      }
      float s0 = a00 + a01, s1 = a10 + a11;
      s0 += __shfl_xor(s0, 1); s0 += __shfl_xor(s0, 2); s0 += __shfl_xor(s0, 4);
      s1 += __shfl_xor(s1, 1); s1 += __shfl_xor(s1, 2); s1 += __shfl_xor(s1, 4);
      if (ks == 0) { WHC[n * 128 + ml] = s0; WHC[n * 128 + ml + 64] = s1; }
    }
    __syncthreads();
  }

  // ---- P4: stage SE[b] transposed: SET[s][132] = SE[b][h][s] ----
  for (int p = 0; p < 16; ++p) {
    int idx = p * 512 + t;
    int h = idx >> 6, s = idx & 63;
    SET[s * 132 + h] = SE[b * 8192 + idx];
  }
  __syncthreads();

  // ---- P5: U_t[m][66] = (W_att1 @ SE^T)[s][m] + dyn-fold (transposed) ----
  {
    int ml = t >> 3, ks = t & 7;
    float4 w0[4], w1[4];
#pragma unroll
    for (int q = 0; q < 4; ++q) {
      w0[q] = *(const float4*)(W_att + (ml)      * 384 + q * 32 + ks * 4);
      w1[q] = *(const float4*)(W_att + (ml + 64) * 384 + q * 32 + ks * 4);
    }
    for (int n = 0; n < SN; ++n) {
      float4 x4[4];
#pragma unroll
      for (int q = 0; q < 4; ++q)
        x4[q] = *(const float4*)(SET + n * 132 + q * 32 + ks * 4);
      float a00 = 0.f, a01 = 0.f, a10 = 0.f, a11 = 0.f;
#pragma unroll
      for (int q = 0; q < 4; ++q) {
        a00 = fmaf(w0[q].x, x4[q].x, a00);
        a01 = fmaf(w0[q].y, x4[q].y, a01);
        a00 = fmaf(w0[q].z, x4[q].z, a00);
        a01 = fmaf(w0[q].w, x4[q].w, a01);
        a10 = fmaf(w1[q].x, x4[q].x, a10);
        a11 = fmaf(w1[q].y, x4[q].y, a11);
        a10 = fmaf(w1[q].z, x4[q].z, a10);
        a11 = fmaf(w1[q].w, x4[q].w, a11);
      }
      float s0 = a00 + a01, s1 = a10 + a11;
      s0 += __shfl_xor(s0, 1); s0 += __shfl_xor(s0, 2); s0 += __shfl_xor(s0, 4);
      s1 += __shfl_xor(s1, 1); s1 += __shfl_xor(s1, 2); s1 += __shfl_xor(s1, 4);
      if (ks == 0) {
        float d0 = DY[n], d1 = DY[64 + n];
        UT[(ml)      * 66 + n] = s0 + WDs[2 * ml] * d0 + WDs[2 * ml + 1] * d1 + CVs[ml];
        UT[(ml + 64) * 66 + n] = s1 + WDs[2 * (ml + 64)] * d0 + WDs[2 * (ml + 64) + 1] * d1 + CVs[ml + 64];
      }
    }
    __syncthreads();
  }

  // ---- P6: scores P[i][s] -> A[0:4096) ----
  {
    int s = t & 63, w = t >> 6;
    for (int it = 0; it < 8; ++it) {
      int i = it * 8 + w;
      float acc = 0.f;
      for (int h = 0; h < HN; h += 4) {
        float u0 = UT[(h + 0) * 66 + s];
        float u1 = UT[(h + 1) * 66 + s];
        float u2 = UT[(h + 2) * 66 + s];
        float u3 = UT[(h + 3) * 66 + s];
        float4 wh = *(const float4*)(WHC + i * 128 + h);
        float4 v4 = *(const float4*)(SV + h);
        acc = fmaf(v4.x, ftanh(u0 + wh.x), acc);
        acc = fmaf(v4.y, ftanh(u1 + wh.y), acc);
        acc = fmaf(v4.z, ftanh(u2 + wh.z), acc);
        acc = fmaf(v4.w, ftanh(u3 + wh.w), acc);
      }
      A[i * 64 + s] = acc;
    }
    __syncthreads();
  }

  // ---- P7: gumbels -> A[4096:8192) ----
  {
    float* G = A + 4096;
    for (int p = 0; p < 8; ++p) {
      int idx = p * 512 + t;
      int i = idx >> 6;
      G[idx] = jax_gumbel(KK[2 * i], KK[2 * i + 1], b * 64 + (idx & 63));
    }
    __syncthreads();
  }

  // ---- P8: serial sampling (wave 0) ----
  if (t < 64) {
    const float* Pl = A;
    const float* Gl = A + 4096;
    int s = t;
    bool visited = false;
    for (int i = 0; i < SN; ++i) {
      float score = Pl[i * 64 + s];
      bool allowed = (i == 0) ? (s == 0) : (!visited);
      float logit = allowed ? score : NEGV;
      float z = logit + Gl[i * 64 + s];
      float bz = z; int bi = s;
#pragma unroll
      for (int off = 32; off > 0; off >>= 1) {
        float oz = __shfl_xor(bz, off);
        int oi = __shfl_xor(bi, off);
        if (oz > bz || (oz == bz && oi < bi)) { bz = oz; bi = oi; }
      }
      int ptr = bi;
      float m = logit;
#pragma unroll
      for (int off = 32; off > 0; off >>= 1) m = fmaxf(m, __shfl_xor(m, off));
      float e = expf(logit - m);
      float sum = e;
#pragma unroll
      for (int off = 32; off > 0; off >>= 1) sum += __shfl_xor(sum, off);
      float chosen = __shfl(logit, ptr);
      float logp = (chosen - m) - logf(sum);
      if (s == ptr) visited = true;
      if (s == 0) {
        out[b * SN + i] = (float)ptr;
        out[BN * SN + b * SN + i] = logp;
      }
    }
  }
}

// ---------------- launch ----------------
extern "C" void kernel_launch(void* const* d_in, const int* in_sizes, int n_in,
                              void* d_out, int out_size, void* d_ws, size_t ws_size,
                              hipStream_t stream) {
  const float* SE    = (const float*)d_in[1];
  const float* dynam = (const float*)d_in[2];
  const float* dyn_w = (const float*)d_in[3];
  const float* dyn_b = (const float*)d_in[4];
  const float* in_w  = (const float*)d_in[5];
  const float* in_b  = (const float*)d_in[6];
  const float* w_ih  = (const float*)d_in[7];
  const float* w_hh  = (const float*)d_in[8];
  const float* b_ih  = (const float*)d_in[9];
  const float* b_hh  = (const float*)d_in[10];
  const float* W_att = (const float*)d_in[11];
  const float* v_att = (const float*)d_in[12];
  float* out = (float*)d_out;
  float* ws = (float*)d_ws;

  float* Wd = ws;        // 256
  float* cv = ws + 256;  // 128

  // opt-in to >64KB dynamic LDS (idempotent; not a stream op, capture-safe)
  (void)hipFuncSetAttribute((const void*)mega,
                            hipFuncAttributeMaxDynamicSharedMemorySize,
                            SMEM_FLOATS * 4);

  hipLaunchKernelGGL(k0_dyn, dim3(1), dim3(128), 0, stream,
                     W_att, dyn_w, dyn_b, Wd, cv);
  hipLaunchKernelGGL(mega, dim3(BN), dim3(512), SMEM_FLOATS * 4, stream,
                     SE, dynam, in_w, in_b, w_ih, b_ih, w_hh, b_hh,
                     W_att, v_att, Wd, cv, out);
}

// Round 9
// 317.939 us; speedup vs baseline: 1.3360x; 1.1296x over previous
//
#include <hip/hip_runtime.h>
#include <stdint.h>

// PointerNetwork forward, MI355X/gfx950 — SINGLE FUSED KERNEL.
// R8 post-mortem: VGPR_Count=76 < 96 regs of declared weight arrays =>
// allocator remat'd weight loads inside inner loops (L2 refetch every
// iteration). R9: amdgpu_waves_per_eu(2,2) (8 waves/CU = 2/EU, truthful)
// raises VGPR budget to 256 so weights stay resident; ks=4x3row chain
// layout (fewer shfl, lane-local GRU tail); P6 loop interchange (U read
// once per h-quad, 8-i register accumulators).
// B=256, S=64, H=128.
// RNG: JAX threefry2x32 partitionable mode: bits = o0^o1 of tf(key,(0,j)).

#define BN 256
#define SN 64
#define HN 128
#define NEGV (-1.0e9f)
#define TINYF 1.17549435e-38f

// LDS layout (floats). Lifetime aliasing:
//  A [0,8192): X (P0-P1) / H (P2-P3) / P+G (P6-P8)
//  B [8192,33280): GI (P1-P2) / WhC@8192, seT@16384, U_t@24832 (P3+)
#define OFF_A   0
#define OFF_GI  8192
#define OFF_WHC 8192
#define OFF_SET 16384
#define OFF_UT  24832
#define OFF_HC  33280   // 2*128 double-buffered x/h state
#define OFF_KK  33536   // 128 (uint32 keys)
#define OFF_SV  33664   // 128 v_att
#define OFF_DY  33792   // 128 dynamic[b]
#define OFF_WD  33920   // 256 Wd
#define OFF_CV  34176   // 128 cv
#define SMEM_FLOATS 34304   // 137216 B

__device__ __forceinline__ uint32_t rotl32(uint32_t v, int d) {
  return (v << d) | (v >> (32 - d));
}

__device__ __forceinline__ void threefry2x32(uint32_t k0, uint32_t k1,
                                             uint32_t x0, uint32_t x1,
                                             uint32_t& o0, uint32_t& o1) {
  uint32_t ks2 = k0 ^ k1 ^ 0x1BD11BDAu;
  x0 += k0; x1 += k1;
  x0 += x1; x1 = rotl32(x1, 13); x1 ^= x0;
  x0 += x1; x1 = rotl32(x1, 15); x1 ^= x0;
  x0 += x1; x1 = rotl32(x1, 26); x1 ^= x0;
  x0 += x1; x1 = rotl32(x1, 6);  x1 ^= x0;
  x0 += k1; x1 += ks2 + 1u;
  x0 += x1; x1 = rotl32(x1, 17); x1 ^= x0;
  x0 += x1; x1 = rotl32(x1, 29); x1 ^= x0;
  x0 += x1; x1 = rotl32(x1, 16); x1 ^= x0;
  x0 += x1; x1 = rotl32(x1, 24); x1 ^= x0;
  x0 += ks2; x1 += k0 + 2u;
  x0 += x1; x1 = rotl32(x1, 13); x1 ^= x0;
  x0 += x1; x1 = rotl32(x1, 15); x1 ^= x0;
  x0 += x1; x1 = rotl32(x1, 26); x1 ^= x0;
  x0 += x1; x1 = rotl32(x1, 6);  x1 ^= x0;
  x0 += k0; x1 += k1 + 3u;
  x0 += x1; x1 = rotl32(x1, 17); x1 ^= x0;
  x0 += x1; x1 = rotl32(x1, 29); x1 ^= x0;
  x0 += x1; x1 = rotl32(x1, 16); x1 ^= x0;
  x0 += x1; x1 = rotl32(x1, 24); x1 ^= x0;
  x0 += k1; x1 += ks2 + 4u;
  x0 += x1; x1 = rotl32(x1, 13); x1 ^= x0;
  x0 += x1; x1 = rotl32(x1, 15); x1 ^= x0;
  x0 += x1; x1 = rotl32(x1, 26); x1 ^= x0;
  x0 += x1; x1 = rotl32(x1, 6);  x1 ^= x0;
  x0 += ks2; x1 += k0 + 5u;
  o0 = x0; o1 = x1;
}

__device__ __forceinline__ float jax_gumbel(uint32_t k0, uint32_t k1, int j) {
  uint32_t o0, o1;
  threefry2x32(k0, k1, 0u, (uint32_t)j, o0, o1);
  uint32_t bits = o0 ^ o1;
  uint32_t ub = (bits >> 9) | 0x3F800000u;
  float u = __uint_as_float(ub) - 1.0f;
  u = fmaxf(u + TINYF, TINYF);
  return -logf(-logf(u));
}

__device__ __forceinline__ float ftanh(float x) {
  float ax = fabsf(x);
  float e = __expf(-2.0f * ax);
  float r = (1.0f - e) * __builtin_amdgcn_rcpf(1.0f + e);
  return copysignf(r, x);
}

__device__ __forceinline__ float fsig(float x) {
  return __builtin_amdgcn_rcpf(1.0f + __expf(-x));
}

// ---------------- K0: fold dyn path through W_att2 (tiny) ----------------
__global__ void k0_dyn(const float* __restrict__ W_att, const float* __restrict__ dyn_w,
                       const float* __restrict__ dyn_b, float* __restrict__ Wd,
                       float* __restrict__ cv) {
  int h = threadIdx.x;  // 128
  float w0 = 0.f, w1 = 0.f, cc = 0.f;
  for (int k = 0; k < HN; ++k) {
    float w = W_att[h * 384 + 128 + k];
    w0 = fmaf(w, dyn_w[2 * k + 0], w0);
    w1 = fmaf(w, dyn_w[2 * k + 1], w1);
    cc = fmaf(w, dyn_b[k], cc);
  }
  Wd[2 * h] = w0; Wd[2 * h + 1] = w1; cv[h] = cc;
}

// ---------------- MEGA: everything for batch b in one block ----------------
__global__ __launch_bounds__(512)
__attribute__((amdgpu_waves_per_eu(2, 2)))
void mega(
    const float* __restrict__ SE, const float* __restrict__ dynamic,
    const float* __restrict__ in_w, const float* __restrict__ in_b,
    const float* __restrict__ w_ih, const float* __restrict__ b_ih,
    const float* __restrict__ w_hh, const float* __restrict__ b_hh,
    const float* __restrict__ W_att, const float* __restrict__ v_att,
    const float* __restrict__ Wd, const float* __restrict__ cv,
    float* __restrict__ out) {
  extern __shared__ float sm[];
  int b = blockIdx.x, t = threadIdx.x;
  float* A   = sm + OFF_A;
  float* GIl = sm + OFF_GI;
  float* WHC = sm + OFF_WHC;
  float* SET = sm + OFF_SET;
  float* UT  = sm + OFF_UT;
  float* HC  = sm + OFF_HC;
  uint32_t* KK = (uint32_t*)(sm + OFF_KK);
  float* SV  = sm + OFF_SV;
  float* DY  = sm + OFF_DY;
  float* WDs = sm + OFF_WD;
  float* CVs = sm + OFF_CV;

  // ---- staging ----
  if (t < 64) {
    uint32_t o0, o1;
    threefry2x32(0u, 42u, 0u, (uint32_t)t, o0, o1);   // fold_in(key(42), i=t)
    KK[2 * t] = o0; KK[2 * t + 1] = o1;
  }
  if (t < 128) {
    SV[t]  = v_att[t];
    DY[t]  = dynamic[b * 128 + t];
    CVs[t] = cv[t];
    HC[t]  = SE[b * 8192 + t * 64];   // x_{-1} = SE[b,:,0] into buf0
  }
  if (t < 256) WDs[t] = Wd[t];
  __syncthreads();

  // ---- P0: x-chain. 512 thr = 128 ml x 4 ks; k-slice q*16+ks*4, q<8 ----
  {
    int ml = t >> 2, ks = t & 3;
    float4 wv[8];
#pragma unroll
    for (int q = 0; q < 8; ++q)
      wv[q] = *(const float4*)(in_w + ml * HN + q * 16 + ks * 4);
    float bib = in_b[ml];
    for (int ii = 0; ii < SN; ++ii) {
      const float* xc = HC + (ii & 1) * 128;
      float* xn = HC + ((ii + 1) & 1) * 128;
      float a0 = 0.f, a1 = 0.f, a2 = 0.f, a3 = 0.f;
#pragma unroll
      for (int q = 0; q < 8; ++q) {
        float4 x4 = *(const float4*)(xc + q * 16 + ks * 4);
        a0 = fmaf(wv[q].x, x4.x, a0);
        a1 = fmaf(wv[q].y, x4.y, a1);
        a2 = fmaf(wv[q].z, x4.z, a2);
        a3 = fmaf(wv[q].w, x4.w, a3);
      }
      float s = (a0 + a1) + (a2 + a3);
      s += __shfl_xor(s, 1); s += __shfl_xor(s, 2);
      if (ks == 0) {
        float xv = s + bib;
        A[ii * 128 + ml] = xv;   // X history
        xn[ml] = xv;
      }
      __syncthreads();
    }
  }

  // ---- P1: GI = w_ih @ X + b_ih (bulk). 128 ml x 4 ks; rows ml+128j ----
  {
    int ml = t >> 2, ks = t & 3;
    float4 wv[3][8]; float bi[3];
#pragma unroll
    for (int j = 0; j < 3; ++j) {
#pragma unroll
      for (int q = 0; q < 8; ++q)
        wv[j][q] = *(const float4*)(w_ih + (ml + 128 * j) * HN + q * 16 + ks * 4);
      bi[j] = b_ih[ml + 128 * j];
    }
    for (int n = 0; n < SN; ++n) {
      float4 x4[8];
#pragma unroll
      for (int q = 0; q < 8; ++q)
        x4[q] = *(const float4*)(A + n * 128 + q * 16 + ks * 4);
      float sum[3];
#pragma unroll
      for (int j = 0; j < 3; ++j) {
        float a0 = 0.f, a1 = 0.f, a2 = 0.f, a3 = 0.f;
#pragma unroll
        for (int q = 0; q < 8; ++q) {
          a0 = fmaf(wv[j][q].x, x4[q].x, a0);
          a1 = fmaf(wv[j][q].y, x4[q].y, a1);
          a2 = fmaf(wv[j][q].z, x4[q].z, a2);
          a3 = fmaf(wv[j][q].w, x4[q].w, a3);
        }
        float s = (a0 + a1) + (a2 + a3);
        s += __shfl_xor(s, 1); s += __shfl_xor(s, 2);
        sum[j] = s + bi[j];
      }
      if (ks == 0) {
#pragma unroll
        for (int j = 0; j < 3; ++j) GIl[n * 384 + ml + 128 * j] = sum[j];
      }
    }
    __syncthreads();
  }

  // ---- P2: h-chain (GRU). 128 ml x 4 ks; rows ml+128j; lane-local tail ----
  if (t < 256) HC[t] = 0.f;
  __syncthreads();
  {
    int ml = t >> 2, ks = t & 3;
    float4 wv[3][8]; float bh[3];
#pragma unroll
    for (int j = 0; j < 3; ++j) {
#pragma unroll
      for (int q = 0; q < 8; ++q)
        wv[j][q] = *(const float4*)(w_hh + (ml + 128 * j) * HN + q * 16 + ks * 4);
      bh[j] = b_hh[ml + 128 * j];
    }
    float hp = 0.f;  // previous h[ml] (ks==0 lanes)
    for (int ii = 0; ii < SN; ++ii) {
      const float* hcr = HC + (ii & 1) * 128;
      float* hcw = HC + ((ii + 1) & 1) * 128;
      float4 x4[8];
#pragma unroll
      for (int q = 0; q < 8; ++q)
        x4[q] = *(const float4*)(hcr + q * 16 + ks * 4);
      float sum[3];
#pragma unroll
      for (int j = 0; j < 3; ++j) {
        float a0 = 0.f, a1 = 0.f, a2 = 0.f, a3 = 0.f;
#pragma unroll
        for (int q = 0; q < 8; ++q) {
          a0 = fmaf(wv[j][q].x, x4[q].x, a0);
          a1 = fmaf(wv[j][q].y, x4[q].y, a1);
          a2 = fmaf(wv[j][q].z, x4[q].z, a2);
          a3 = fmaf(wv[j][q].w, x4[q].w, a3);
        }
        float s = (a0 + a1) + (a2 + a3);
        s += __shfl_xor(s, 1); s += __shfl_xor(s, 2);
        sum[j] = s + bh[j];
      }
      if (ks == 0) {
        const float* gr = GIl + ii * 384;
        float r = fsig(gr[ml] + sum[0]);
        float z = fsig(gr[128 + ml] + sum[1]);
        float nn = ftanh(gr[256 + ml] + r * sum[2]);
        float hn = (1.0f - z) * nn + z * hp;
        hcw[ml] = hn;
        A[ii * 128 + ml] = hn;   // H history
        hp = hn;
      }
      __syncthreads();
    }
  }

  // ---- P3: WhC = W_att3 @ H (bulk). 64 ml x 8 ks; 2 m-rows ----
  {
    int ml = t >> 3, ks = t & 7;
    float4 w0[4], w1[4];
#pragma unroll
    for (int q = 0; q < 4; ++q) {
      w0[q] = *(const float4*)(W_att + (ml)      * 384 + 256 + q * 32 + ks * 4);
      w1[q] = *(const float4*)(W_att + (ml + 64) * 384 + 256 + q * 32 + ks * 4);
    }
    for (int n = 0; n < SN; ++n) {
      float4 x4[4];
#pragma unroll
      for (int q = 0; q < 4; ++q)
        x4[q] = *(const float4*)(A + n * 128 + q * 32 + ks * 4);
      float a00 = 0.f, a01 = 0.f, a10 = 0.f, a11 = 0.f;
#pragma unroll
      for (int q = 0; q < 4; ++q) {
        a00 = fmaf(w0[q].x, x4[q].x, a00);
        a01 = fmaf(w0[q].y, x4[q].y, a01);
        a00 = fmaf(w0[q].z, x4[q].z, a00);
        a01 = fmaf(w0[q].w, x4[q].w, a01);
        a10 = fmaf(w1[q].x, x4[q].x, a10);
        a11 = fmaf(w1[q].y, x4[q].y, a11);
        a10 = fmaf(w1[q].z, x4[q].z, a10);
        a11 = fmaf(w1[q].w, x4[q].w, a11);
      }
      float s0 = a00 + a01, s1 = a10 + a11;
      s0 += __shfl_xor(s0, 1); s0 += __shfl_xor(s0, 2); s0 += __shfl_xor(s0, 4);
      s1 += __shfl_xor(s1, 1); s1 += __shfl_xor(s1, 2); s1 += __shfl_xor(s1, 4);
      if (ks == 0) { WHC[n * 128 + ml] = s0; WHC[n * 128 + ml + 64] = s1; }
    }
    __syncthreads();
  }

  // ---- P4: stage SE[b] transposed: SET[s][132] = SE[b][h][s] ----
  for (int p = 0; p < 16; ++p) {
    int idx = p * 512 + t;
    int h = idx >> 6, s = idx & 63;
    SET[s * 132 + h] = SE[b * 8192 + idx];
  }
  __syncthreads();

  // ---- P5: U_t[m][66] = (W_att1 @ SE^T)[s][m] + dyn-fold (transposed) ----
  {
    int ml = t >> 3, ks = t & 7;
    float4 w0[4], w1[4];
#pragma unroll
    for (int q = 0; q < 4; ++q) {
      w0[q] = *(const float4*)(W_att + (ml)      * 384 + q * 32 + ks * 4);
      w1[q] = *(const float4*)(W_att + (ml + 64) * 384 + q * 32 + ks * 4);
    }
    for (int n = 0; n < SN; ++n) {
      float4 x4[4];
#pragma unroll
      for (int q = 0; q < 4; ++q)
        x4[q] = *(const float4*)(SET + n * 132 + q * 32 + ks * 4);
      float a00 = 0.f, a01 = 0.f, a10 = 0.f, a11 = 0.f;
#pragma unroll
      for (int q = 0; q < 4; ++q) {
        a00 = fmaf(w0[q].x, x4[q].x, a00);
        a01 = fmaf(w0[q].y, x4[q].y, a01);
        a00 = fmaf(w0[q].z, x4[q].z, a00);
        a01 = fmaf(w0[q].w, x4[q].w, a01);
        a10 = fmaf(w1[q].x, x4[q].x, a10);
        a11 = fmaf(w1[q].y, x4[q].y, a11);
        a10 = fmaf(w1[q].z, x4[q].z, a10);
        a11 = fmaf(w1[q].w, x4[q].w, a11);
      }
      float s0 = a00 + a01, s1 = a10 + a11;
      s0 += __shfl_xor(s0, 1); s0 += __shfl_xor(s0, 2); s0 += __shfl_xor(s0, 4);
      s1 += __shfl_xor(s1, 1); s1 += __shfl_xor(s1, 2); s1 += __shfl_xor(s1, 4);
      if (ks == 0) {
        float d0 = DY[n], d1 = DY[64 + n];
        UT[(ml)      * 66 + n] = s0 + WDs[2 * ml] * d0 + WDs[2 * ml + 1] * d1 + CVs[ml];
        UT[(ml + 64) * 66 + n] = s1 + WDs[2 * (ml + 64)] * d0 + WDs[2 * (ml + 64) + 1] * d1 + CVs[ml + 64];
      }
    }
    __syncthreads();
  }

  // ---- P6: scores P[i][s] -> A[0:4096). Loop-interchanged: u once/quad ----
  {
    int s = t & 63, w = t >> 6;   // wave w owns i = w*8 + j, j<8
    float acc[8];
#pragma unroll
    for (int j = 0; j < 8; ++j) acc[j] = 0.f;
    for (int h = 0; h < HN; h += 4) {
      float u0 = UT[(h + 0) * 66 + s];
      float u1 = UT[(h + 1) * 66 + s];
      float u2 = UT[(h + 2) * 66 + s];
      float u3 = UT[(h + 3) * 66 + s];
      float4 v4 = *(const float4*)(SV + h);
#pragma unroll
      for (int j = 0; j < 8; ++j) {
        float4 wh = *(const float4*)(WHC + (w * 8 + j) * 128 + h);
        float a = acc[j];
        a = fmaf(v4.x, ftanh(u0 + wh.x), a);
        a = fmaf(v4.y, ftanh(u1 + wh.y), a);
        a = fmaf(v4.z, ftanh(u2 + wh.z), a);
        a = fmaf(v4.w, ftanh(u3 + wh.w), a);
        acc[j] = a;
      }
    }
    __syncthreads();  // UT/WHC reads done; A (aliases H) now rewritable
#pragma unroll
    for (int j = 0; j < 8; ++j) A[(w * 8 + j) * 64 + s] = acc[j];
    __syncthreads();
  }

  // ---- P7: gumbels -> A[4096:8192) ----
  {
    float* G = A + 4096;
    for (int p = 0; p < 8; ++p) {
      int idx = p * 512 + t;
      int i = idx >> 6;
      G[idx] = jax_gumbel(KK[2 * i], KK[2 * i + 1], b * 64 + (idx & 63));
    }
    __syncthreads();
  }

  // ---- P8: serial sampling (wave 0) ----
  if (t < 64) {
    const float* Pl = A;
    const float* Gl = A + 4096;
    int s = t;
    bool visited = false;
    for (int i = 0; i < SN; ++i) {
      float score = Pl[i * 64 + s];
      bool allowed = (i == 0) ? (s == 0) : (!visited);
      float logit = allowed ? score : NEGV;
      float z = logit + Gl[i * 64 + s];
      float bz = z; int bi = s;
#pragma unroll
      for (int off = 32; off > 0; off >>= 1) {
        float oz = __shfl_xor(bz, off);
        int oi = __shfl_xor(bi, off);
        if (oz > bz || (oz == bz && oi < bi)) { bz = oz; bi = oi; }
      }
      int ptr = bi;
      float m = logit;
#pragma unroll
      for (int off = 32; off > 0; off >>= 1) m = fmaxf(m, __shfl_xor(m, off));
      float e = expf(logit - m);
      float sum = e;
#pragma unroll
      for (int off = 32; off > 0; off >>= 1) sum += __shfl_xor(sum, off);
      float chosen = __shfl(logit, ptr);
      float logp = (chosen - m) - logf(sum);
      if (s == ptr) visited = true;
      if (s == 0) {
        out[b * SN + i] = (float)ptr;
        out[BN * SN + b * SN + i] = logp;
      }
    }
  }
}

// ---------------- launch ----------------
extern "C" void kernel_launch(void* const* d_in, const int* in_sizes, int n_in,
                              void* d_out, int out_size, void* d_ws, size_t ws_size,
                              hipStream_t stream) {
  const float* SE    = (const float*)d_in[1];
  const float* dynam = (const float*)d_in[2];
  const float* dyn_w = (const float*)d_in[3];
  const float* dyn_b = (const float*)d_in[4];
  const float* in_w  = (const float*)d_in[5];
  const float* in_b  = (const float*)d_in[6];
  const float* w_ih  = (const float*)d_in[7];
  const float* b_ih  = (const float*)d_in[8 - 1];  // placeholder (unused)
  const float* w_hh  = (const float*)d_in[8];
  const float* b_ih2 = (const float*)d_in[9];
  const float* b_hh  = (const float*)d_in[10];
  const float* W_att = (const float*)d_in[11];
  const float* v_att = (const float*)d_in[12];
  float* out = (float*)d_out;
  float* ws = (float*)d_ws;

  float* Wd = ws;        // 256
  float* cv = ws + 256;  // 128

  // opt-in to >64KB dynamic LDS (idempotent; not a stream op, capture-safe)
  (void)hipFuncSetAttribute((const void*)mega,
                            hipFuncAttributeMaxDynamicSharedMemorySize,
                            SMEM_FLOATS * 4);

  hipLaunchKernelGGL(k0_dyn, dim3(1), dim3(128), 0, stream,
                     W_att, dyn_w, dyn_b, Wd, cv);
  hipLaunchKernelGGL(mega, dim3(BN), dim3(512), SMEM_FLOATS * 4, stream,
                     SE, dynam, in_w, in_b, w_ih, b_ih2, w_hh, b_hh,
                     W_att, v_att, Wd, cv, out);
}